// Round 1
// baseline (179.203 us; speedup 1.0000x reference)
//
#include <hip/hip_runtime.h>
#include <hip/hip_bf16.h>

// Word embedding gather: out[token, :] = weight[ids[token], :]
// ids: (4*2048,) int32 ; weight: (32000, 1024) fp32 ; out: (8192, 1024) fp32
// DIM = 1024 floats = 256 float4 per row. One block (256 threads) per token:
// each thread moves exactly one float4 (16 B/lane, ideal coalescing).

#define DIM4 256  // 1024 floats / 4 per float4

__global__ __launch_bounds__(256) void embed_gather_kernel(
    const int* __restrict__ ids,
    const float4* __restrict__ weight,
    float4* __restrict__ out,
    int n_tokens)
{
    const int token = blockIdx.x;
    if (token >= n_tokens) return;
    const int id = ids[token];  // wave-uniform per block (all lanes same token)
    const float4* __restrict__ src = weight + (size_t)id * DIM4;
    float4* __restrict__ dst = out + (size_t)token * DIM4;
    dst[threadIdx.x] = src[threadIdx.x];
}

extern "C" void kernel_launch(void* const* d_in, const int* in_sizes, int n_in,
                              void* d_out, int out_size, void* d_ws, size_t ws_size,
                              hipStream_t stream) {
    const int*    ids    = (const int*)d_in[0];      // input_ids, 4*2048 int32
    const float4* weight = (const float4*)d_in[1];   // (32000, 1024) fp32
    float4*       out    = (float4*)d_out;           // (8192, 1024) fp32

    const int n_tokens = in_sizes[0];                // 8192

    embed_gather_kernel<<<n_tokens, DIM4, 0, stream>>>(ids, weight, out, n_tokens);
}